// Round 21
// baseline (186.151 us; speedup 1.0000x reference)
//
#include <hip/hip_runtime.h>
#include <hip/hip_bf16.h>

// Multi-head attention: x[16,1024,768] fp32, W_qkv[768,2304], b_qkv[2304],
// W_out[768,768], b_out[768] -> out[16,1024,768] fp32.
// Pipeline:
//   1) tcvt:  W_qkv, W_out -> transposed bf16
//   2) gemm2f: qkv = x @ W_qkv + b reading x FP32 DIRECTLY (A reg-staged:
//      global fp32 loads -> v_cvt_pk_bf16_f32 -> ds_write; B via glds;
//      counted-vmcnt, triple-buffered). Q/K -> qkvb rows; V -> vtb transposed.
//      (cvt_x kernel deleted.)
//   3) attn: 32x32 MFMA, sigma-permuted padded K, double-buffered K/V LDS
//   4) gemm2<1>: out = attn @ W_out + b_out -> fp32 (bf16-A glds path)

#define DEVINL __device__ __forceinline__

typedef __attribute__((ext_vector_type(8))) short s16x8;
typedef __attribute__((ext_vector_type(4))) short s16x4;
typedef __attribute__((ext_vector_type(4))) float f32x4;
typedef __attribute__((ext_vector_type(16))) float f32x16;

DEVINL short f2bf(float f) {
  union { float f; unsigned u; } c; c.f = f;
  unsigned r = c.u + 0x7FFFu + ((c.u >> 16) & 1u);
  return (short)(r >> 16);
}
DEVINL float asf(unsigned u) {
  union { unsigned u; float f; } c; c.u = u; return c.f;
}
// truncating pack (P-weights only; lsum uses the SAME truncated values)
DEVINL unsigned pack2(float a, float b) {
  union { float f; unsigned u; } ca, cb; ca.f = a; cb.f = b;
  return (ca.u >> 16) | (cb.u & 0xffff0000u);
}
DEVINL int swap23(int k) { return (k & ~12) | ((k & 4) << 1) | ((k & 8) >> 1); }

DEVINL void gload_lds16(const short* g, short* lds) {
  __builtin_amdgcn_global_load_lds((const __attribute__((address_space(1))) void*)g,
                                   (__attribute__((address_space(3))) void*)lds, 16, 0, 0);
}

// ---------------- conversion kernel ----------------

__global__ void tcvt_kernel(const float* __restrict__ in, short* __restrict__ out, int R, int C) {
  __shared__ float t[32][33];
  int tx = threadIdx.x & 31, ty = threadIdx.x >> 5;
  int r0 = blockIdx.y * 32, c0 = blockIdx.x * 32;
#pragma unroll
  for (int i = 0; i < 4; i++) {
    int r = ty + i * 8;
    t[r][tx] = in[(size_t)(r0 + r) * C + c0 + tx];
  }
  __syncthreads();
#pragma unroll
  for (int i = 0; i < 4; i++) {
    int r = ty + i * 8;
    out[(size_t)(c0 + r) * R + r0 + tx] = f2bf(t[tx][r]);
  }
}

// ---------------- GEMM qkv: fp32 A, BM=256, BN=128, BK=32, 8 waves, 2 blocks/CU --------
// A reg-staged: iter kt issues 4 global_load_dwordx4 (fp32 cols of tile kt+1,
// both quadrants) at the TOP; after MFMAs, WAITV(1) (retires A(kt+1) + B(kt+1)
// glds, keeps B(kt+2) in flight), then v_cvt_pk_bf16_f32 x8 -> 2 ds_write_b128
// into buf[(kt+1)%3], lgkmcnt(0) publish, barrier. B stays glds 2-ahead
// (round-15-verified). WAR: A region of buf[(kt+1)%3] last read two barriers
// ago. Tails: WAITV(0) at kt==NKT-2; no write at NKT-1.
// Epilogue (round-17 verified): Q/K relayout -> qkvb rows; V per-wave 64x64
// transpose -> vtb.

__global__ __launch_bounds__(512, 4) void gemm2f(const float* __restrict__ Ax, const short* __restrict__ Bt,
                                                 const float* __restrict__ bias, int nTn,
                                                 short* __restrict__ qkvb, short* __restrict__ vtb) {
  __shared__ short lds[36864];          // 72KB: A [3][2][4096] + B [3][4096]
  short* const ldsA = lds;
  short* const ldsB = lds + 24576;
  const int tid = threadIdx.x;
  const int l = tid & 63, w = tid >> 6;
  const int lo = l & 15, hi = l >> 4;
  const int wm = w >> 1, wn = w & 1;

  int cpx = gridDim.x >> 3;
  int bid = blockIdx.x;
  int swz = (bid & 7) * cpx + (bid >> 3);
  int tm = swz / nTn, tn = swz - tm * nTn;

  const int NKT = 24;  // K=768

  const int Ls = tid >> 3, s7 = tid & 7;
  const int pS = (s7 >> 2) & 1;
  const int cS = (s7 & 3) ^ (Ls & 3);
  const int rho = 2 * Ls + pS;
  const int gA = ((rho >> 5) << 6) + (rho & 31);
  const float* aF = Ax + (size_t)(tm * 256 + gA) * 768 + cS * 8;
  const short* bS = Bt + (size_t)(tn * 128 + rho) * 768 + cS * 8;
  short* const bD = ldsB + tid * 8;

  float4 ar0, ar1, ar2, ar3;  // A-hold: q0 {ar0,ar1}, q1 {ar2,ar3}

#define L_A(j) do {                                                   \
    const float* p_ = aF + (j) * 32;                                  \
    ar0 = *(const float4*)p_;                                         \
    ar1 = *(const float4*)(p_ + 4);                                   \
    ar2 = *(const float4*)(p_ + 32 * 768);                            \
    ar3 = *(const float4*)(p_ + 32 * 768 + 4); } while (0)

#define CVTPK(d, a, b) asm("v_cvt_pk_bf16_f32 %0, %1, %2" : "=v"(d) : "v"(a), "v"(b))

#define CW_A(bs) do {                                                 \
    union { unsigned w4[4]; s16x8 v; } t0_, t1_;                      \
    CVTPK(t0_.w4[0], ar0.x, ar0.y); CVTPK(t0_.w4[1], ar0.z, ar0.w);   \
    CVTPK(t0_.w4[2], ar1.x, ar1.y); CVTPK(t0_.w4[3], ar1.z, ar1.w);   \
    CVTPK(t1_.w4[0], ar2.x, ar2.y); CVTPK(t1_.w4[1], ar2.z, ar2.w);   \
    CVTPK(t1_.w4[2], ar3.x, ar3.y); CVTPK(t1_.w4[3], ar3.z, ar3.w);   \
    *(s16x8*)(ldsA + ((bs) * 2 + 0) * 4096 + tid * 8) = t0_.v;        \
    *(s16x8*)(ldsA + ((bs) * 2 + 1) * 4096 + tid * 8) = t1_.v; } while (0)

#define ST_B(j, bs) gload_lds16(bS + (j) * 32, bD + (bs) * 4096)

  const int LaBase = wm * 16 + (lo >> 1);
  const int LbBase = wn * 32 + (lo >> 1);
  const int pp = (lo & 1) << 2;

  f32x4 acc[4][4] = {};

#define RD_A(AF, bc, qm) do {                                                    \
    const short* base_ = ldsA + ((bc) * 2 + (qm)) * 4096;                        \
    _Pragma("unroll") for (int mi = 0; mi < 2; mi++) {                           \
      int La_ = LaBase + mi * 8;                                                 \
      AF[mi] = *(const s16x8*)(base_ + La_ * 64 + (((hi ^ (La_ & 3)) + pp) << 3)); } } while (0)
#define RD_B(BF, bc) do {                                                        \
    const short* base_ = ldsB + (bc) * 4096;                                     \
    _Pragma("unroll") for (int b = 0; b < 4; b++) {                              \
      int Lb_ = LbBase + b * 8;                                                  \
      BF[b] = *(const s16x8*)(base_ + Lb_ * 64 + (((hi ^ (Lb_ & 3)) + pp) << 3)); } } while (0)

#define MM8(a0, AF, BF) do {                                                     \
    __builtin_amdgcn_s_setprio(1);                                               \
    _Pragma("unroll") for (int mi = 0; mi < 2; mi++)                             \
      _Pragma("unroll") for (int b = 0; b < 4; b++)                              \
        acc[(a0) + mi][b] = __builtin_amdgcn_mfma_f32_16x16x32_bf16(             \
            AF[mi], BF[b], acc[(a0) + mi][b], 0, 0, 0);                          \
    __builtin_amdgcn_s_setprio(0); } while (0)

#define WAITV(n) asm volatile("s_waitcnt vmcnt(" #n ")" ::: "memory")
#define WAITL() asm volatile("s_waitcnt lgkmcnt(0)" ::: "memory")
#define BARR() do { __builtin_amdgcn_sched_barrier(0); __builtin_amdgcn_s_barrier(); \
                    __builtin_amdgcn_sched_barrier(0); } while (0)

  // prologue: A(0) regs; B(0)->buf0, B(1)->buf1 glds; drain to B(0); write A(0)
  L_A(0);
  ST_B(0, 0); ST_B(1, 1);
  WAITV(1);        // retires A(0) x4 + B(0); leaves B(1)
  CW_A(0);
  WAITL();
  __builtin_amdgcn_s_barrier();

  s16x8 af[2], bf[4];
  int bc = 0;
#pragma unroll 1
  for (int kt = 0; kt < NKT; kt++) {
    int bn = (bc == 2) ? 0 : bc + 1;      // (kt+1)%3: A write target
    int bs = (bc == 0) ? 2 : bc - 1;      // (kt+2)%3: B glds target
    if (kt + 1 < NKT) L_A(kt + 1);
    if (kt + 2 < NKT) ST_B(kt + 2, bs);
    RD_A(af, bc, 0);
    RD_B(bf, bc);
    MM8(0, af, bf);
    RD_A(af, bc, 1);
    MM8(2, af, bf);
    if (kt + 1 < NKT) {
      if (kt + 2 < NKT) { WAITV(1); } else { WAITV(0); }
      CW_A(bn);
      WAITL();
    }
    BARR();
    bc = bn;
  }
#undef L_A
#undef CVTPK
#undef CW_A
#undef ST_B
#undef RD_A
#undef RD_B
#undef MM8
#undef WAITV
#undef WAITL
#undef BARR

  {
    const float qscale = 0.14724444757204526f;  // 96^-0.5 * log2(e)
    __syncthreads();
    if (tn < 12) {
      // Q/K tiles: [256][128] relayout, coalesced row stores to qkvb
#pragma unroll
      for (int b = 0; b < 4; b++) {
        int colr = wn * 64 + b * 16 + lo;
        int coln = tn * 128 + colr;
        float bv = bias[coln];
        float scl = (coln < 768) ? qscale : 1.0f;
#pragma unroll
        for (int a = 0; a < 4; a++)
#pragma unroll
          for (int j = 0; j < 4; j++) {
            int rowr = wm * 64 + a * 16 + hi * 4 + j;
            lds[rowr * 128 + colr] = f2bf((acc[a][b][j] + bv) * scl);
          }
      }
      __syncthreads();
      short* dstb = qkvb + (size_t)(tm * 256) * 2304 + tn * 128;
#pragma unroll
      for (int k = 0; k < 8; k++) {
        int g = k * 512 + tid;
        int r = g >> 4, c = g & 15;
        *(s16x8*)(dstb + (size_t)r * 2304 + c * 8) = *(const s16x8*)(lds + r * 128 + c * 8);
      }
    } else {
      // V tiles: per-wave 64x64 transpose -> vtb[(b*8+h)*96+dd][1024 n]
      short* scr = lds + w * 4096;
#pragma unroll
      for (int b = 0; b < 4; b++) {
        int c = b * 16 + lo;
        float bv = bias[tn * 128 + wn * 64 + c];
#pragma unroll
        for (int a = 0; a < 4; a++)
#pragma unroll
          for (int j = 0; j < 4; j++) {
            int row = a * 16 + hi * 4 + j;
            scr[row * 64 + (c ^ (((row >> 3) & 7) << 3))] = f2bf(acc[a][b][j] + bv);
          }
      }
      int r8 = l >> 3, k8 = l & 7;
      int n0 = k8 * 8;
      int rowg = tm * 256 + wm * 64;
      int bb = rowg >> 10;
      int nb = (rowg & 1023) + n0;
#pragma unroll
      for (int p = 0; p < 8; p++) {
        int c = p * 8 + r8;
        int inner = tn * 128 + wn * 64 + c - 1536;
        int hh = inner / 96;
        int dd = inner - hh * 96;
        union { short v[8]; s16x8 x; } t;
#pragma unroll
        for (int j = 0; j < 8; j++)
          t.v[j] = scr[(n0 + j) * 64 + (c ^ (k8 << 3))];
        *(s16x8*)(vtb + ((size_t)(bb * 8 + hh) * 96 + dd) * 1024 + nb) = t.x;
      }
    }
  }
}

// ---------------- GEMM (bf16 A): out-projection, round-15/16 verified ----------------

__global__ __launch_bounds__(512, 4) void gemm2(const short* __restrict__ A, const short* __restrict__ Bt,
                                                const float* __restrict__ bias, int K, int nTn,
                                                float* __restrict__ outf) {
  __shared__ short lds[36864];
  short* const ldsA = lds;
  short* const ldsB = lds + 24576;
  const int tid = threadIdx.x;
  const int l = tid & 63, w = tid >> 6;
  const int lo = l & 15, hi = l >> 4;
  const int wm = w >> 1, wn = w & 1;

  int cpx = gridDim.x >> 3;
  int bid = blockIdx.x;
  int swz = (bid & 7) * cpx + (bid >> 3);
  int tm = swz / nTn, tn = swz - tm * nTn;

  const int NKT = K >> 5;

  const int Ls = tid >> 3, s7 = tid & 7;
  const int pS = (s7 >> 2) & 1;
  const int cS = (s7 & 3) ^ (Ls & 3);
  const int rho = 2 * Ls + pS;
  const int gA = ((rho >> 5) << 6) + (rho & 31);
  const short* aS0 = A + (size_t)(tm * 256 + gA) * K + cS * 8;
  const short* aS1 = aS0 + (size_t)32 * K;
  const short* bS = Bt + (size_t)(tn * 128 + rho) * K + cS * 8;

#define ST_A(j, q, bs) gload_lds16(((q) ? aS1 : aS0) + (j) * 32, ldsA + ((bs) * 2 + (q)) * 4096 + tid * 8)
#define ST_B(j, bs)    gload_lds16(bS + (j) * 32, ldsB + (bs) * 4096 + tid * 8)

  const int LaBase = wm * 16 + (lo >> 1);
  const int LbBase = wn * 32 + (lo >> 1);
  const int pp = (lo & 1) << 2;

  f32x4 acc[4][4] = {};

#define RD_A(AF, bc, qm) do {                                                    \
    const short* base_ = ldsA + ((bc) * 2 + (qm)) * 4096;                        \
    _Pragma("unroll") for (int mi = 0; mi < 2; mi++) {                           \
      int La_ = LaBase + mi * 8;                                                 \
      AF[mi] = *(const s16x8*)(base_ + La_ * 64 + (((hi ^ (La_ & 3)) + pp) << 3)); } } while (0)
#define RD_B(BF, bc) do {                                                        \
    const short* base_ = ldsB + (bc) * 4096;                                     \
    _Pragma("unroll") for (int b = 0; b < 4; b++) {                              \
      int Lb_ = LbBase + b * 8;                                                  \
      BF[b] = *(const s16x8*)(base_ + Lb_ * 64 + (((hi ^ (Lb_ & 3)) + pp) << 3)); } } while (0)

#define MM8(a0, AF, BF) do {                                                     \
    __builtin_amdgcn_s_setprio(1);                                               \
    _Pragma("unroll") for (int mi = 0; mi < 2; mi++)                             \
      _Pragma("unroll") for (int b = 0; b < 4; b++)                              \
        acc[(a0) + mi][b] = __builtin_amdgcn_mfma_f32_16x16x32_bf16(             \
            AF[mi], BF[b], acc[(a0) + mi][b], 0, 0, 0);                          \
    __builtin_amdgcn_s_setprio(0); } while (0)

#define WAITV(n) asm volatile("s_waitcnt vmcnt(" #n ")" ::: "memory")
#define BARR() do { __builtin_amdgcn_sched_barrier(0); __builtin_amdgcn_s_barrier(); \
                    __builtin_amdgcn_sched_barrier(0); } while (0)

  ST_A(0, 0, 0); ST_B(0, 0); ST_A(0, 1, 0);
  ST_A(1, 0, 1); ST_B(1, 1); ST_A(1, 1, 1);
  WAITV(3);
  __builtin_amdgcn_s_barrier();

  s16x8 af[2], bf[4];
  int bc = 0;
#pragma unroll 1
  for (int kt = 0; kt < NKT; kt++) {
    int bs = (bc == 0) ? 2 : bc - 1;
    RD_A(af, bc, 0);
    RD_B(bf, bc);
    if (kt + 2 < NKT) { ST_A(kt + 2, 0, bs); ST_B(kt + 2, bs); }
    MM8(0, af, bf);
    RD_A(af, bc, 1);
    if (kt + 2 < NKT) ST_A(kt + 2, 1, bs);
    MM8(2, af, bf);
    if (kt + 2 < NKT) {
      WAITV(3);
    } else if (kt + 2 == NKT) {
      WAITV(0);
    }
    BARR();
    bc = (bc == 2) ? 0 : bc + 1;
  }
#undef ST_A
#undef ST_B
#undef RD_A
#undef RD_B
#undef MM8
#undef WAITV
#undef BARR

#pragma unroll
  for (int b = 0; b < 4; b++) {
    int coln = tn * 128 + wn * 64 + b * 16 + lo;
    float bv = bias[coln];
#pragma unroll
    for (int a = 0; a < 4; a++)
#pragma unroll
      for (int j = 0; j < 4; j++) {
        int rowm = tm * 256 + wm * 64 + a * 16 + hi * 4 + j;
        outf[(size_t)rowm * 768 + coln] = acc[a][b][j] + bv;
      }
  }
}

// ---------------- attention (32x32 MFMA, sigma K, double-buffered LDS; round-20) --------

__global__ __launch_bounds__(256) void attn_kernel(const short* __restrict__ qkvb,
                                                   const short* __restrict__ vtb,
                                                   short* __restrict__ attn_out) {
  __shared__ short Klds[2 * 64 * 104];
  __shared__ short Vlds[2 * 96 * 64];
  const int KOFF = 64 * 104, VOFF = 96 * 64;
  int tid = threadIdx.x, lane = tid & 63, wid = tid >> 6;
  int q31 = lane & 31, hi2 = lane >> 5;
  int bid = blockIdx.x;
  int pair = bid & 127, qt = bid >> 7;
  int b = pair >> 3, h = pair & 7;
  const short* Vtp = vtb + (size_t)pair * 1024 * 96;
  int qrow0 = qt * 128 + wid * 32;

  s16x8 qf[6];
#pragma unroll
  for (int dc = 0; dc < 6; dc++)
    qf[dc] = *(const s16x8*)(qkvb + (size_t)(b * 1024 + qrow0 + q31) * 2304 +
                             h * 96 + dc * 16 + hi2 * 8);

  const short* sp[6];
  short* sdst[6];
  int sstep[6], boff[6];
#pragma unroll
  for (int i = 0; i < 6; i++) {
    if (i < 3) {
      int c = i * 256 + tid;
      int krow = c / 12, kcc = c - krow * 12;
      int lam = swap23(krow);
      sdst[i] = Klds + lam * 104 + kcc * 8;
      sp[i] = qkvb + (size_t)(b * 1024 + krow) * 2304 + 768 + h * 96 + kcc * 8;
      sstep[i] = 64 * 2304;
      boff[i] = KOFF;
    } else {
      int d = (i - 3) * 256 + tid;
      int vrow = d >> 3, vcc = d & 7;
      sdst[i] = Vlds + vrow * 64 + ((vcc ^ (vrow & 7)) << 3);
      sp[i] = Vtp + (size_t)vrow * 1024 + vcc * 8;
      sstep[i] = 64;
      boff[i] = VOFF;
    }
  }

  f32x16 accO[3] = {};
  float lsum = 0.0f;

  s16x8 sreg[6];
#pragma unroll
  for (int i = 0; i < 6; i++) sreg[i] = *(const s16x8*)sp[i];
#pragma unroll
  for (int i = 0; i < 6; i++) *(s16x8*)sdst[i] = sreg[i];
#pragma unroll
  for (int i = 0; i < 6; i++) sreg[i] = *(const s16x8*)(sp[i] + (size_t)sstep[i]);
  __syncthreads();

  for (int t = 0; t < 16; t++) {
    int cur = t & 1, nxt = (t + 1) & 1;
    if (t < 15) {
#pragma unroll
      for (int i = 0; i < 6; i++) *(s16x8*)(sdst[i] + nxt * boff[i]) = sreg[i];
      int t2 = (t + 2) & 15;
#pragma unroll
      for (int i = 0; i < 6; i++)
        sreg[i] = *(const s16x8*)(sp[i] + (size_t)t2 * sstep[i]);
    }

    const short* Kb = Klds + cur * KOFF;
    const short* Vb = Vlds + cur * VOFF;
#pragma unroll
    for (int kb = 0; kb < 2; kb++) {
      f32x16 st = {};
      __builtin_amdgcn_s_setprio(1);
#pragma unroll
      for (int dc = 0; dc < 6; dc++) {
        int c = dc * 2 + hi2;
        int lam = kb * 32 + q31;
        s16x8 kf = *(const s16x8*)(Kb + lam * 104 + c * 8);
        st = __builtin_amdgcn_mfma_f32_32x32x16_bf16(kf, qf[dc], st, 0, 0, 0);
      }
      __builtin_amdgcn_s_setprio(0);

      unsigned u[8];
#pragma unroll
      for (int i = 0; i < 8; i++) {
        float p0 = __builtin_amdgcn_exp2f(st[2 * i]);
        float p1 = __builtin_amdgcn_exp2f(st[2 * i + 1]);
        unsigned w = pack2(p0, p1);
        u[i] = w;
        lsum += asf(w << 16) + asf(w & 0xffff0000u);
      }

      __builtin_amdgcn_s_setprio(1);
#pragma unroll
      for (int half = 0; half < 2; half++) {
        union { unsigned w[4]; s16x8 v; } pa;
#pragma unroll
        for (int wi = 0; wi < 4; wi++) pa.w[wi] = u[half * 4 + wi];
        int kc = kb * 2 + half;
#pragma unroll
        for (int db = 0; db < 3; db++) {
          int d = db * 32 + q31;
          s16x8 vf = *(const s16x8*)(Vb + d * 64 + (((kc * 2 + hi2) ^ (d & 7)) << 3));
          accO[db] = __builtin_amdgcn_mfma_f32_32x32x16_bf16(pa.v, vf, accO[db], 0, 0, 0);
        }
      }
      __builtin_amdgcn_s_setprio(0);
    }
    __syncthreads();
  }

  float s = lsum + __shfl_xor(lsum, 32, 64);
  float rinv = 1.0f / s;
  float rr[16];
#pragma unroll
  for (int r = 0; r < 16; r++)
    rr[r] = __shfl(rinv, (r & 3) + 8 * (r >> 2) + 4 * hi2, 64);

#pragma unroll
  for (int db = 0; db < 3; db++)
#pragma unroll
    for (int r = 0; r < 16; r++) {
      int qrow = qrow0 + (r & 3) + 8 * (r >> 2) + 4 * hi2;
      int d = db * 32 + q31;
      attn_out[((size_t)b * 1024 + qrow) * 768 + h * 96 + d] = f2bf(accO[db][r] * rr[r]);
    }
}

// ---------------- launch ----------------

extern "C" void kernel_launch(void* const* d_in, const int* in_sizes, int n_in,
                              void* d_out, int out_size, void* d_ws, size_t ws_size,
                              hipStream_t stream) {
  const float* x = (const float*)d_in[0];
  const float* Wqkv = (const float*)d_in[1];
  const float* bqkv = (const float*)d_in[2];
  const float* Wout = (const float*)d_in[3];
  const float* bout = (const float*)d_in[4];
  float* out = (float*)d_out;

  char* ws = (char*)d_ws;
  // layout (bytes), total 130,547,712:
  //   xb    @ 0          : 25,165,824  (bf16 attn_out [B][N][768])
  //   wqkvT @ 25165824   :  3,538,944
  //   woutT @ 28704768   :  1,179,648
  //   qkvb  @ 29884416   : 75,497,472  ([16384][2304] bf16; V region unused)
  //   vtb   @ 105381888  : 25,165,824  ([pair][96][1024] bf16)
  short* xb = (short*)ws;
  short* wqkvT = (short*)(ws + 25165824);
  short* woutT = (short*)(ws + 28704768);
  short* qkvb = (short*)(ws + 29884416);
  short* vtb = (short*)(ws + 105381888);

  tcvt_kernel<<<dim3(72, 24), 256, 0, stream>>>(Wqkv, wqkvT, 768, 2304);
  tcvt_kernel<<<dim3(24, 24), 256, 0, stream>>>(Wout, woutT, 768, 768);

  // qkv: M=16384 (64 tiles), N=2304 (18 tiles) -> 1152 blocks (mult of 8); fp32 A
  gemm2f<<<1152, 512, 0, stream>>>(x, wqkvT, bqkv, 18, qkvb, vtb);
  attn_kernel<<<1024, 256, 0, stream>>>(qkvb, vtb, xb);
  // out: M=16384 (64), N=768 (6) -> 384 blocks (mult of 8)
  gemm2<<<384, 512, 0, stream>>>(xb, woutT, bout, 768, 6, out);
}

// Round 22
// 182.797 us; speedup vs baseline: 1.0183x; 1.0183x over previous
//
#include <hip/hip_runtime.h>
#include <hip/hip_bf16.h>

// Multi-head attention: x[16,1024,768] fp32, W_qkv[768,2304], b_qkv[2304],
// W_out[768,768], b_out[768] -> out[16,1024,768] fp32.
// Pipeline (round-20 verified configuration — session optimum):
//   1) cvt_x: x -> bf16
//   2) tcvt:  W_qkv, W_out -> transposed bf16
//   3) gemm2<0>: qkv = x @ W_qkv + b; BM256xBN128xBK32, triple-buffered,
//      2 blocks/CU. Q/K tiles -> qkvb rows; V tiles -> vtb transposed (fused)
//   4) attn: 32x32 MFMA, sigma-permuted padded K, double-buffered K/V LDS
//   5) gemm2<1>: out = attn @ W_out + b_out -> fp32

#define DEVINL __device__ __forceinline__

typedef __attribute__((ext_vector_type(8))) short s16x8;
typedef __attribute__((ext_vector_type(4))) short s16x4;
typedef __attribute__((ext_vector_type(4))) float f32x4;
typedef __attribute__((ext_vector_type(16))) float f32x16;

DEVINL short f2bf(float f) {
  union { float f; unsigned u; } c; c.f = f;
  unsigned r = c.u + 0x7FFFu + ((c.u >> 16) & 1u);
  return (short)(r >> 16);
}
DEVINL float asf(unsigned u) {
  union { unsigned u; float f; } c; c.u = u; return c.f;
}
// truncating pack (P-weights only; lsum uses the SAME truncated values)
DEVINL unsigned pack2(float a, float b) {
  union { float f; unsigned u; } ca, cb; ca.f = a; cb.f = b;
  return (ca.u >> 16) | (cb.u & 0xffff0000u);
}
DEVINL int swap23(int k) { return (k & ~12) | ((k & 4) << 1) | ((k & 8) >> 1); }

DEVINL void gload_lds16(const short* g, short* lds) {
  __builtin_amdgcn_global_load_lds((const __attribute__((address_space(1))) void*)g,
                                   (__attribute__((address_space(3))) void*)lds, 16, 0, 0);
}

// ---------------- conversion kernels ----------------

__global__ void cvt_x_kernel(const float* __restrict__ in, short* __restrict__ out) {
  int i = blockIdx.x * 256 + threadIdx.x;
  float4 v = ((const float4*)in)[i];
  s16x4 o = { f2bf(v.x), f2bf(v.y), f2bf(v.z), f2bf(v.w) };
  *(s16x4*)(out + (size_t)i * 4) = o;
}

__global__ void tcvt_kernel(const float* __restrict__ in, short* __restrict__ out, int R, int C) {
  __shared__ float t[32][33];
  int tx = threadIdx.x & 31, ty = threadIdx.x >> 5;
  int r0 = blockIdx.y * 32, c0 = blockIdx.x * 32;
#pragma unroll
  for (int i = 0; i < 4; i++) {
    int r = ty + i * 8;
    t[r][tx] = in[(size_t)(r0 + r) * C + c0 + tx];
  }
  __syncthreads();
#pragma unroll
  for (int i = 0; i < 4; i++) {
    int r = ty + i * 8;
    out[(size_t)(c0 + r) * R + r0 + tx] = f2bf(t[tx][r]);
  }
}

// ---------------- GEMM BM=256, BN=128, BK=32, 8 waves, 2 blocks/CU ----------------
// Triple-buffered (round-15/16 verified, incl. tail drain). Epilogues: Q/K via
// [256][128] LDS relayout; V via per-wave 64x64 transpose scratch (round-17).

template <int MODE>
__global__ __launch_bounds__(512, 4) void gemm2(const short* __restrict__ A, const short* __restrict__ Bt,
                                                const float* __restrict__ bias, int K, int nTn,
                                                short* __restrict__ qkvb, short* __restrict__ vtb,
                                                float* __restrict__ outf) {
  __shared__ short lds[36864];          // 72KB: loop 3x24KB; epilogue relayout/scratch
  short* const ldsA = lds;              // [3 buf][2 q][4096]
  short* const ldsB = lds + 24576;      // [3 buf][4096]
  const int tid = threadIdx.x;
  const int l = tid & 63, w = tid >> 6;
  const int lo = l & 15, hi = l >> 4;
  const int wm = w >> 1, wn = w & 1;

  // XCD-aware bijective swizzle (gridDim.x % 8 == 0)
  int cpx = gridDim.x >> 3;
  int bid = blockIdx.x;
  int swz = (bid & 7) * cpx + (bid >> 3);
  int tm = swz / nTn, tn = swz - tm * nTn;

  const int NKT = K >> 5;

  // staging source (pair-swizzled): thread -> line L, slot s7
  const int Ls = tid >> 3, s7 = tid & 7;
  const int pS = (s7 >> 2) & 1;
  const int cS = (s7 & 3) ^ (Ls & 3);
  const int rho = 2 * Ls + pS;                      // region-row / col index [0,128)
  const int gA = ((rho >> 5) << 6) + (rho & 31);    // A row in tile (q adds +32)
  const short* aS0 = A + (size_t)(tm * 256 + gA) * K + cS * 8;
  const short* aS1 = aS0 + (size_t)32 * K;
  const short* bS = Bt + (size_t)(tn * 128 + rho) * K + cS * 8;

#define ST_A(j, q, bs) gload_lds16(((q) ? aS1 : aS0) + (j) * 32, ldsA + ((bs) * 2 + (q)) * 4096 + tid * 8)
#define ST_B(j, bs)    gload_lds16(bS + (j) * 32, ldsB + (bs) * 4096 + tid * 8)

  const int LaBase = wm * 16 + (lo >> 1);   // + mi*8
  const int LbBase = wn * 32 + (lo >> 1);   // + b*8
  const int pp = (lo & 1) << 2;

  f32x4 acc[4][4] = {};

#define RD_A(AF, bc, qm) do {                                                    \
    const short* base_ = ldsA + ((bc) * 2 + (qm)) * 4096;                        \
    _Pragma("unroll") for (int mi = 0; mi < 2; mi++) {                           \
      int La_ = LaBase + mi * 8;                                                 \
      AF[mi] = *(const s16x8*)(base_ + La_ * 64 + (((hi ^ (La_ & 3)) + pp) << 3)); } } while (0)
#define RD_B(BF, bc) do {                                                        \
    const short* base_ = ldsB + (bc) * 4096;                                     \
    _Pragma("unroll") for (int b = 0; b < 4; b++) {                              \
      int Lb_ = LbBase + b * 8;                                                  \
      BF[b] = *(const s16x8*)(base_ + Lb_ * 64 + (((hi ^ (Lb_ & 3)) + pp) << 3)); } } while (0)

#define MM8(a0, AF, BF) do {                                                     \
    __builtin_amdgcn_s_setprio(1);                                               \
    _Pragma("unroll") for (int mi = 0; mi < 2; mi++)                             \
      _Pragma("unroll") for (int b = 0; b < 4; b++)                              \
        acc[(a0) + mi][b] = __builtin_amdgcn_mfma_f32_16x16x32_bf16(             \
            AF[mi], BF[b], acc[(a0) + mi][b], 0, 0, 0);                          \
    __builtin_amdgcn_s_setprio(0); } while (0)

#define WAITV(n) asm volatile("s_waitcnt vmcnt(" #n ")" ::: "memory")
#define BARR() do { __builtin_amdgcn_sched_barrier(0); __builtin_amdgcn_s_barrier(); \
                    __builtin_amdgcn_sched_barrier(0); } while (0)

  // prologue: tiles 0 and 1 staged fully (tile order preserved for vmcnt)
  ST_A(0, 0, 0); ST_B(0, 0); ST_A(0, 1, 0);
  ST_A(1, 0, 1); ST_B(1, 1); ST_A(1, 1, 1);
  WAITV(3);      // tile 0's three loads retired
  __builtin_amdgcn_s_barrier();

  s16x8 af[2], bf[4];
  int bc = 0;
#pragma unroll 1
  for (int kt = 0; kt < NKT; kt++) {
    int bs = (bc == 0) ? 2 : bc - 1;        // (kt+2) % 3
    RD_A(af, bc, 0);
    RD_B(bf, bc);
    if (kt + 2 < NKT) { ST_A(kt + 2, 0, bs); ST_B(kt + 2, bs); }
    MM8(0, af, bf);
    RD_A(af, bc, 1);
    if (kt + 2 < NKT) ST_A(kt + 2, 1, bs);
    MM8(2, af, bf);
    if (kt + 2 < NKT) {
      WAITV(3);                 // retires tile kt+1's loads (3 newest = tile kt+2)
    } else if (kt + 2 == NKT) {
      WAITV(0);                 // tail: no newer loads; drain tile NKT-1 fully
    }
    BARR();
    bc = (bc == 2) ? 0 : bc + 1;
  }
#undef ST_A
#undef ST_B
#undef RD_A
#undef RD_B
#undef MM8
#undef WAITV
#undef BARR

  if (MODE == 0) {
    const float qscale = 0.14724444757204526f;  // 96^-0.5 * log2(e)
    __syncthreads();
    if (tn < 12) {
      // Q/K tiles: [256][128] relayout, coalesced row stores to qkvb
#pragma unroll
      for (int b = 0; b < 4; b++) {
        int colr = wn * 64 + b * 16 + lo;
        int coln = tn * 128 + colr;
        float bv = bias[coln];
        float scl = (coln < 768) ? qscale : 1.0f;
#pragma unroll
        for (int a = 0; a < 4; a++)
#pragma unroll
          for (int j = 0; j < 4; j++) {
            int rowr = wm * 64 + a * 16 + hi * 4 + j;
            lds[rowr * 128 + colr] = f2bf((acc[a][b][j] + bv) * scl);
          }
      }
      __syncthreads();
      short* dstb = qkvb + (size_t)(tm * 256) * 2304 + tn * 128;
#pragma unroll
      for (int k = 0; k < 8; k++) {
        int g = k * 512 + tid;
        int r = g >> 4, c = g & 15;
        *(s16x8*)(dstb + (size_t)r * 2304 + c * 8) = *(const s16x8*)(lds + r * 128 + c * 8);
      }
    } else {
      // V tiles: per-wave 64x64 transpose -> vtb[(b*8+h)*96+dd][1024 n]
      short* scr = lds + w * 4096;  // 8KB/wave, wave-private
#pragma unroll
      for (int b = 0; b < 4; b++) {
        int c = b * 16 + lo;
        float bv = bias[tn * 128 + wn * 64 + c];
#pragma unroll
        for (int a = 0; a < 4; a++)
#pragma unroll
          for (int j = 0; j < 4; j++) {
            int row = a * 16 + hi * 4 + j;                 // local n
            scr[row * 64 + (c ^ (((row >> 3) & 7) << 3))] = f2bf(acc[a][b][j] + bv);
          }
      }
      int r8 = l >> 3, k8 = l & 7;
      int n0 = k8 * 8;
      int rowg = tm * 256 + wm * 64;
      int bb = rowg >> 10;
      int nb = (rowg & 1023) + n0;
#pragma unroll
      for (int p = 0; p < 8; p++) {
        int c = p * 8 + r8;
        int inner = tn * 128 + wn * 64 + c - 1536;         // [0,768)
        int hh = inner / 96;
        int dd = inner - hh * 96;
        union { short v[8]; s16x8 x; } t;
#pragma unroll
        for (int j = 0; j < 8; j++)
          t.v[j] = scr[(n0 + j) * 64 + (c ^ (k8 << 3))];
        *(s16x8*)(vtb + ((size_t)(bb * 8 + hh) * 96 + dd) * 1024 + nb) = t.x;
      }
    }
  } else {
#pragma unroll
    for (int b = 0; b < 4; b++) {
      int coln = tn * 128 + wn * 64 + b * 16 + lo;
      float bv = bias[coln];
#pragma unroll
      for (int a = 0; a < 4; a++)
#pragma unroll
        for (int j = 0; j < 4; j++) {
          int rowm = tm * 256 + wm * 64 + a * 16 + hi * 4 + j;
          outf[(size_t)rowm * 768 + coln] = acc[a][b][j] + bv;
        }
    }
  }
}

// ---------------- attention (32x32 MFMA, sigma K, double-buffered LDS; round-20) --------
// grid: 1024 blocks x 256 threads; pair = bid&127 (pair-major XCD swizzle),
// qt = bid>>7. 4 waves x 32 q-rows. Q pre-scaled into exp2 domain.
// K LDS [2][64][104] padded; V LDS [2][96][64] XOR-chunk. One barrier per
// tile: iteration t computes from buf[t&1] while writing tile t+1's staged
// registers into buf[(t+1)&1]; barrier orders WAR and publishes for t+1.

__global__ __launch_bounds__(256) void attn_kernel(const short* __restrict__ qkvb,
                                                   const short* __restrict__ vtb,
                                                   short* __restrict__ attn_out) {
  __shared__ short Klds[2 * 64 * 104];
  __shared__ short Vlds[2 * 96 * 64];
  const int KOFF = 64 * 104, VOFF = 96 * 64;
  int tid = threadIdx.x, lane = tid & 63, wid = tid >> 6;
  int q31 = lane & 31, hi2 = lane >> 5;
  int bid = blockIdx.x;
  int pair = bid & 127, qt = bid >> 7;
  int b = pair >> 3, h = pair & 7;
  const short* Vtp = vtb + (size_t)pair * 1024 * 96;  // [96][1024]
  int qrow0 = qt * 128 + wid * 32;

  s16x8 qf[6];
#pragma unroll
  for (int dc = 0; dc < 6; dc++)
    qf[dc] = *(const s16x8*)(qkvb + (size_t)(b * 1024 + qrow0 + q31) * 2304 +
                             h * 96 + dc * 16 + hi2 * 8);

  const short* sp[6];
  short* sdst[6];
  int sstep[6], boff[6];
#pragma unroll
  for (int i = 0; i < 6; i++) {
    if (i < 3) {
      int c = i * 256 + tid;
      int krow = c / 12, kcc = c - krow * 12;
      int lam = swap23(krow);
      sdst[i] = Klds + lam * 104 + kcc * 8;
      sp[i] = qkvb + (size_t)(b * 1024 + krow) * 2304 + 768 + h * 96 + kcc * 8;
      sstep[i] = 64 * 2304;
      boff[i] = KOFF;
    } else {
      int d = (i - 3) * 256 + tid;
      int vrow = d >> 3, vcc = d & 7;
      sdst[i] = Vlds + vrow * 64 + ((vcc ^ (vrow & 7)) << 3);
      sp[i] = Vtp + (size_t)vrow * 1024 + vcc * 8;
      sstep[i] = 64;
      boff[i] = VOFF;
    }
  }

  f32x16 accO[3] = {};
  float lsum = 0.0f;

  s16x8 sreg[6];
#pragma unroll
  for (int i = 0; i < 6; i++) sreg[i] = *(const s16x8*)sp[i];
#pragma unroll
  for (int i = 0; i < 6; i++) *(s16x8*)sdst[i] = sreg[i];
#pragma unroll
  for (int i = 0; i < 6; i++) sreg[i] = *(const s16x8*)(sp[i] + (size_t)sstep[i]);
  __syncthreads();

  for (int t = 0; t < 16; t++) {
    int cur = t & 1, nxt = (t + 1) & 1;
    if (t < 15) {
#pragma unroll
      for (int i = 0; i < 6; i++) *(s16x8*)(sdst[i] + nxt * boff[i]) = sreg[i];
      int t2 = (t + 2) & 15;
#pragma unroll
      for (int i = 0; i < 6; i++)
        sreg[i] = *(const s16x8*)(sp[i] + (size_t)t2 * sstep[i]);
    }

    const short* Kb = Klds + cur * KOFF;
    const short* Vb = Vlds + cur * VOFF;
#pragma unroll
    for (int kb = 0; kb < 2; kb++) {
      f32x16 st = {};
      __builtin_amdgcn_s_setprio(1);
#pragma unroll
      for (int dc = 0; dc < 6; dc++) {
        int c = dc * 2 + hi2;
        int lam = kb * 32 + q31;
        s16x8 kf = *(const s16x8*)(Kb + lam * 104 + c * 8);
        st = __builtin_amdgcn_mfma_f32_32x32x16_bf16(kf, qf[dc], st, 0, 0, 0);
      }
      __builtin_amdgcn_s_setprio(0);

      unsigned u[8];
#pragma unroll
      for (int i = 0; i < 8; i++) {
        float p0 = __builtin_amdgcn_exp2f(st[2 * i]);
        float p1 = __builtin_amdgcn_exp2f(st[2 * i + 1]);
        unsigned w = pack2(p0, p1);
        u[i] = w;
        lsum += asf(w << 16) + asf(w & 0xffff0000u);
      }

      __builtin_amdgcn_s_setprio(1);
#pragma unroll
      for (int half = 0; half < 2; half++) {
        union { unsigned w[4]; s16x8 v; } pa;
#pragma unroll
        for (int wi = 0; wi < 4; wi++) pa.w[wi] = u[half * 4 + wi];
        int kc = kb * 2 + half;
#pragma unroll
        for (int db = 0; db < 3; db++) {
          int d = db * 32 + q31;
          s16x8 vf = *(const s16x8*)(Vb + d * 64 + (((kc * 2 + hi2) ^ (d & 7)) << 3));
          accO[db] = __builtin_amdgcn_mfma_f32_32x32x16_bf16(pa.v, vf, accO[db], 0, 0, 0);
        }
      }
      __builtin_amdgcn_s_setprio(0);
    }
    __syncthreads();
  }

  float s = lsum + __shfl_xor(lsum, 32, 64);
  float rinv = 1.0f / s;
  float rr[16];
#pragma unroll
  for (int r = 0; r < 16; r++)
    rr[r] = __shfl(rinv, (r & 3) + 8 * (r >> 2) + 4 * hi2, 64);

#pragma unroll
  for (int db = 0; db < 3; db++)
#pragma unroll
    for (int r = 0; r < 16; r++) {
      int qrow = qrow0 + (r & 3) + 8 * (r >> 2) + 4 * hi2;
      int d = db * 32 + q31;
      attn_out[((size_t)b * 1024 + qrow) * 768 + h * 96 + d] = f2bf(accO[db][r] * rr[r]);
    }
}

// ---------------- launch ----------------

extern "C" void kernel_launch(void* const* d_in, const int* in_sizes, int n_in,
                              void* d_out, int out_size, void* d_ws, size_t ws_size,
                              hipStream_t stream) {
  const float* x = (const float*)d_in[0];
  const float* Wqkv = (const float*)d_in[1];
  const float* bqkv = (const float*)d_in[2];
  const float* Wout = (const float*)d_in[3];
  const float* bout = (const float*)d_in[4];
  float* out = (float*)d_out;

  char* ws = (char*)d_ws;
  // layout (bytes), total 130,547,712:
  //   xb    @ 0          : 25,165,824  (bf16 x; later reused as attn_out [B][N][768])
  //   wqkvT @ 25165824   :  3,538,944
  //   woutT @ 28704768   :  1,179,648
  //   qkvb  @ 29884416   : 75,497,472  ([16384][2304] bf16; V region unused)
  //   vtb   @ 105381888  : 25,165,824  ([pair][96][1024] bf16)
  short* xb = (short*)ws;
  short* wqkvT = (short*)(ws + 25165824);
  short* woutT = (short*)(ws + 28704768);
  short* qkvb = (short*)(ws + 29884416);
  short* vtb = (short*)(ws + 105381888);

  cvt_x_kernel<<<12288, 256, 0, stream>>>(x, xb);
  tcvt_kernel<<<dim3(72, 24), 256, 0, stream>>>(Wqkv, wqkvT, 768, 2304);
  tcvt_kernel<<<dim3(24, 24), 256, 0, stream>>>(Wout, woutT, 768, 768);

  // qkv: M=16384 (64 tiles), N=2304 (18 tiles) -> 1152 blocks (mult of 8)
  gemm2<0><<<1152, 512, 0, stream>>>(xb, wqkvT, bqkv, 768, 18, qkvb, vtb, nullptr);
  attn_kernel<<<1024, 256, 0, stream>>>(qkvb, vtb, xb);
  // out: M=16384 (64), N=768 (6) -> 384 blocks (mult of 8)
  gemm2<1><<<384, 512, 0, stream>>>(xb, woutT, bout, 768, 6, nullptr, nullptr, out);
}

// Round 23
// 179.783 us; speedup vs baseline: 1.0354x; 1.0168x over previous
//
#include <hip/hip_runtime.h>
#include <hip/hip_bf16.h>

// Multi-head attention: x[16,1024,768] fp32, W_qkv[768,2304], b_qkv[2304],
// W_out[768,768], b_out[768] -> out[16,1024,768] fp32.
// Pipeline (round-22 optimum + fused prep dispatch):
//   1) prep: ONE dispatch -> x->bf16 (xb), W_qkv^T->bf16, W_out^T->bf16
//   2) gemm2<0>: qkv = x @ W_qkv + b; BM256xBN128xBK32, triple-buffered,
//      2 blocks/CU. Q/K tiles -> qkvb rows; V tiles -> vtb transposed (fused)
//   3) attn: 32x32 MFMA, sigma-permuted padded K, double-buffered K/V LDS
//   4) gemm2<1>: out = attn @ W_out + b_out -> fp32

#define DEVINL __device__ __forceinline__

typedef __attribute__((ext_vector_type(8))) short s16x8;
typedef __attribute__((ext_vector_type(4))) short s16x4;
typedef __attribute__((ext_vector_type(4))) float f32x4;
typedef __attribute__((ext_vector_type(16))) float f32x16;

DEVINL short f2bf(float f) {
  union { float f; unsigned u; } c; c.f = f;
  unsigned r = c.u + 0x7FFFu + ((c.u >> 16) & 1u);
  return (short)(r >> 16);
}
DEVINL float asf(unsigned u) {
  union { unsigned u; float f; } c; c.u = u; return c.f;
}
// truncating pack (P-weights only; lsum uses the SAME truncated values)
DEVINL unsigned pack2(float a, float b) {
  union { float f; unsigned u; } ca, cb; ca.f = a; cb.f = b;
  return (ca.u >> 16) | (cb.u & 0xffff0000u);
}
DEVINL int swap23(int k) { return (k & ~12) | ((k & 4) << 1) | ((k & 8) >> 1); }

DEVINL void gload_lds16(const short* g, short* lds) {
  __builtin_amdgcn_global_load_lds((const __attribute__((address_space(1))) void*)g,
                                   (__attribute__((address_space(3))) void*)lds, 16, 0, 0);
}

// ---------------- fused prep kernel ----------------
// grid 14592 x 256:
//   bid <  12288            : x -> bf16 (float4 per thread)
//   12288 <= bid < 14016    : W_qkv [768][2304] -> wqkvT [2304][768] bf16
//   14016 <= bid            : W_out [768][768]  -> woutT [768][768]  bf16

__global__ void prep_kernel(const float* __restrict__ x, short* __restrict__ xb,
                            const float* __restrict__ Wqkv, short* __restrict__ wqkvT,
                            const float* __restrict__ Wout, short* __restrict__ woutT) {
  __shared__ float t[32][33];
  int bid = blockIdx.x, tid = threadIdx.x;
  if (bid < 12288) {
    int i = bid * 256 + tid;
    float4 v = ((const float4*)x)[i];
    s16x4 o = { f2bf(v.x), f2bf(v.y), f2bf(v.z), f2bf(v.w) };
    *(s16x4*)(xb + (size_t)i * 4) = o;
    return;
  }
  const float* in;
  short* out;
  int R, C, gx, gy;
  if (bid < 14016) {
    int rem = bid - 12288;          // 72 x 24 tiles
    gx = rem % 72; gy = rem / 72;
    in = Wqkv; out = wqkvT; R = 768; C = 2304;
  } else {
    int rem = bid - 14016;          // 24 x 24 tiles
    gx = rem % 24; gy = rem / 24;
    in = Wout; out = woutT; R = 768; C = 768;
  }
  int tx = tid & 31, ty = tid >> 5;
  int r0 = gy * 32, c0 = gx * 32;
#pragma unroll
  for (int i = 0; i < 4; i++) {
    int r = ty + i * 8;
    t[r][tx] = in[(size_t)(r0 + r) * C + c0 + tx];
  }
  __syncthreads();
#pragma unroll
  for (int i = 0; i < 4; i++) {
    int r = ty + i * 8;
    out[(size_t)(c0 + r) * R + r0 + tx] = f2bf(t[tx][r]);
  }
}

// ---------------- GEMM BM=256, BN=128, BK=32, 8 waves, 2 blocks/CU ----------------
// Triple-buffered (round-15/16 verified, incl. tail drain). Epilogues: Q/K via
// [256][128] LDS relayout; V via per-wave 64x64 transpose scratch (round-17).

template <int MODE>
__global__ __launch_bounds__(512, 4) void gemm2(const short* __restrict__ A, const short* __restrict__ Bt,
                                                const float* __restrict__ bias, int K, int nTn,
                                                short* __restrict__ qkvb, short* __restrict__ vtb,
                                                float* __restrict__ outf) {
  __shared__ short lds[36864];          // 72KB: loop 3x24KB; epilogue relayout/scratch
  short* const ldsA = lds;              // [3 buf][2 q][4096]
  short* const ldsB = lds + 24576;      // [3 buf][4096]
  const int tid = threadIdx.x;
  const int l = tid & 63, w = tid >> 6;
  const int lo = l & 15, hi = l >> 4;
  const int wm = w >> 1, wn = w & 1;

  // XCD-aware bijective swizzle (gridDim.x % 8 == 0)
  int cpx = gridDim.x >> 3;
  int bid = blockIdx.x;
  int swz = (bid & 7) * cpx + (bid >> 3);
  int tm = swz / nTn, tn = swz - tm * nTn;

  const int NKT = K >> 5;

  // staging source (pair-swizzled): thread -> line L, slot s7
  const int Ls = tid >> 3, s7 = tid & 7;
  const int pS = (s7 >> 2) & 1;
  const int cS = (s7 & 3) ^ (Ls & 3);
  const int rho = 2 * Ls + pS;                      // region-row / col index [0,128)
  const int gA = ((rho >> 5) << 6) + (rho & 31);    // A row in tile (q adds +32)
  const short* aS0 = A + (size_t)(tm * 256 + gA) * K + cS * 8;
  const short* aS1 = aS0 + (size_t)32 * K;
  const short* bS = Bt + (size_t)(tn * 128 + rho) * K + cS * 8;

#define ST_A(j, q, bs) gload_lds16(((q) ? aS1 : aS0) + (j) * 32, ldsA + ((bs) * 2 + (q)) * 4096 + tid * 8)
#define ST_B(j, bs)    gload_lds16(bS + (j) * 32, ldsB + (bs) * 4096 + tid * 8)

  const int LaBase = wm * 16 + (lo >> 1);   // + mi*8
  const int LbBase = wn * 32 + (lo >> 1);   // + b*8
  const int pp = (lo & 1) << 2;

  f32x4 acc[4][4] = {};

#define RD_A(AF, bc, qm) do {                                                    \
    const short* base_ = ldsA + ((bc) * 2 + (qm)) * 4096;                        \
    _Pragma("unroll") for (int mi = 0; mi < 2; mi++) {                           \
      int La_ = LaBase + mi * 8;                                                 \
      AF[mi] = *(const s16x8*)(base_ + La_ * 64 + (((hi ^ (La_ & 3)) + pp) << 3)); } } while (0)
#define RD_B(BF, bc) do {                                                        \
    const short* base_ = ldsB + (bc) * 4096;                                     \
    _Pragma("unroll") for (int b = 0; b < 4; b++) {                              \
      int Lb_ = LbBase + b * 8;                                                  \
      BF[b] = *(const s16x8*)(base_ + Lb_ * 64 + (((hi ^ (Lb_ & 3)) + pp) << 3)); } } while (0)

#define MM8(a0, AF, BF) do {                                                     \
    __builtin_amdgcn_s_setprio(1);                                               \
    _Pragma("unroll") for (int mi = 0; mi < 2; mi++)                             \
      _Pragma("unroll") for (int b = 0; b < 4; b++)                              \
        acc[(a0) + mi][b] = __builtin_amdgcn_mfma_f32_16x16x32_bf16(             \
            AF[mi], BF[b], acc[(a0) + mi][b], 0, 0, 0);                          \
    __builtin_amdgcn_s_setprio(0); } while (0)

#define WAITV(n) asm volatile("s_waitcnt vmcnt(" #n ")" ::: "memory")
#define BARR() do { __builtin_amdgcn_sched_barrier(0); __builtin_amdgcn_s_barrier(); \
                    __builtin_amdgcn_sched_barrier(0); } while (0)

  // prologue: tiles 0 and 1 staged fully (tile order preserved for vmcnt)
  ST_A(0, 0, 0); ST_B(0, 0); ST_A(0, 1, 0);
  ST_A(1, 0, 1); ST_B(1, 1); ST_A(1, 1, 1);
  WAITV(3);      // tile 0's three loads retired
  __builtin_amdgcn_s_barrier();

  s16x8 af[2], bf[4];
  int bc = 0;
#pragma unroll 1
  for (int kt = 0; kt < NKT; kt++) {
    int bs = (bc == 0) ? 2 : bc - 1;        // (kt+2) % 3
    RD_A(af, bc, 0);
    RD_B(bf, bc);
    if (kt + 2 < NKT) { ST_A(kt + 2, 0, bs); ST_B(kt + 2, bs); }
    MM8(0, af, bf);
    RD_A(af, bc, 1);
    if (kt + 2 < NKT) ST_A(kt + 2, 1, bs);
    MM8(2, af, bf);
    if (kt + 2 < NKT) {
      WAITV(3);                 // retires tile kt+1's loads (3 newest = tile kt+2)
    } else if (kt + 2 == NKT) {
      WAITV(0);                 // tail: no newer loads; drain tile NKT-1 fully
    }
    BARR();
    bc = (bc == 2) ? 0 : bc + 1;
  }
#undef ST_A
#undef ST_B
#undef RD_A
#undef RD_B
#undef MM8
#undef WAITV
#undef BARR

  if (MODE == 0) {
    const float qscale = 0.14724444757204526f;  // 96^-0.5 * log2(e)
    __syncthreads();
    if (tn < 12) {
      // Q/K tiles: [256][128] relayout, coalesced row stores to qkvb
#pragma unroll
      for (int b = 0; b < 4; b++) {
        int colr = wn * 64 + b * 16 + lo;
        int coln = tn * 128 + colr;
        float bv = bias[coln];
        float scl = (coln < 768) ? qscale : 1.0f;
#pragma unroll
        for (int a = 0; a < 4; a++)
#pragma unroll
          for (int j = 0; j < 4; j++) {
            int rowr = wm * 64 + a * 16 + hi * 4 + j;
            lds[rowr * 128 + colr] = f2bf((acc[a][b][j] + bv) * scl);
          }
      }
      __syncthreads();
      short* dstb = qkvb + (size_t)(tm * 256) * 2304 + tn * 128;
#pragma unroll
      for (int k = 0; k < 8; k++) {
        int g = k * 512 + tid;
        int r = g >> 4, c = g & 15;
        *(s16x8*)(dstb + (size_t)r * 2304 + c * 8) = *(const s16x8*)(lds + r * 128 + c * 8);
      }
    } else {
      // V tiles: per-wave 64x64 transpose -> vtb[(b*8+h)*96+dd][1024 n]
      short* scr = lds + w * 4096;  // 8KB/wave, wave-private
#pragma unroll
      for (int b = 0; b < 4; b++) {
        int c = b * 16 + lo;
        float bv = bias[tn * 128 + wn * 64 + c];
#pragma unroll
        for (int a = 0; a < 4; a++)
#pragma unroll
          for (int j = 0; j < 4; j++) {
            int row = a * 16 + hi * 4 + j;                 // local n
            scr[row * 64 + (c ^ (((row >> 3) & 7) << 3))] = f2bf(acc[a][b][j] + bv);
          }
      }
      int r8 = l >> 3, k8 = l & 7;
      int n0 = k8 * 8;
      int rowg = tm * 256 + wm * 64;
      int bb = rowg >> 10;
      int nb = (rowg & 1023) + n0;
#pragma unroll
      for (int p = 0; p < 8; p++) {
        int c = p * 8 + r8;
        int inner = tn * 128 + wn * 64 + c - 1536;         // [0,768)
        int hh = inner / 96;
        int dd = inner - hh * 96;
        union { short v[8]; s16x8 x; } t;
#pragma unroll
        for (int j = 0; j < 8; j++)
          t.v[j] = scr[(n0 + j) * 64 + (c ^ (k8 << 3))];
        *(s16x8*)(vtb + ((size_t)(bb * 8 + hh) * 96 + dd) * 1024 + nb) = t.x;
      }
    }
  } else {
#pragma unroll
    for (int b = 0; b < 4; b++) {
      int coln = tn * 128 + wn * 64 + b * 16 + lo;
      float bv = bias[coln];
#pragma unroll
      for (int a = 0; a < 4; a++)
#pragma unroll
        for (int j = 0; j < 4; j++) {
          int rowm = tm * 256 + wm * 64 + a * 16 + hi * 4 + j;
          outf[(size_t)rowm * 768 + coln] = acc[a][b][j] + bv;
        }
    }
  }
}

// ---------------- attention (32x32 MFMA, sigma K, double-buffered LDS; round-20) --------

__global__ __launch_bounds__(256) void attn_kernel(const short* __restrict__ qkvb,
                                                   const short* __restrict__ vtb,
                                                   short* __restrict__ attn_out) {
  __shared__ short Klds[2 * 64 * 104];
  __shared__ short Vlds[2 * 96 * 64];
  const int KOFF = 64 * 104, VOFF = 96 * 64;
  int tid = threadIdx.x, lane = tid & 63, wid = tid >> 6;
  int q31 = lane & 31, hi2 = lane >> 5;
  int bid = blockIdx.x;
  int pair = bid & 127, qt = bid >> 7;
  int b = pair >> 3, h = pair & 7;
  const short* Vtp = vtb + (size_t)pair * 1024 * 96;  // [96][1024]
  int qrow0 = qt * 128 + wid * 32;

  s16x8 qf[6];
#pragma unroll
  for (int dc = 0; dc < 6; dc++)
    qf[dc] = *(const s16x8*)(qkvb + (size_t)(b * 1024 + qrow0 + q31) * 2304 +
                             h * 96 + dc * 16 + hi2 * 8);

  const short* sp[6];
  short* sdst[6];
  int sstep[6], boff[6];
#pragma unroll
  for (int i = 0; i < 6; i++) {
    if (i < 3) {
      int c = i * 256 + tid;
      int krow = c / 12, kcc = c - krow * 12;
      int lam = swap23(krow);
      sdst[i] = Klds + lam * 104 + kcc * 8;
      sp[i] = qkvb + (size_t)(b * 1024 + krow) * 2304 + 768 + h * 96 + kcc * 8;
      sstep[i] = 64 * 2304;
      boff[i] = KOFF;
    } else {
      int d = (i - 3) * 256 + tid;
      int vrow = d >> 3, vcc = d & 7;
      sdst[i] = Vlds + vrow * 64 + ((vcc ^ (vrow & 7)) << 3);
      sp[i] = Vtp + (size_t)vrow * 1024 + vcc * 8;
      sstep[i] = 64;
      boff[i] = VOFF;
    }
  }

  f32x16 accO[3] = {};
  float lsum = 0.0f;

  s16x8 sreg[6];
#pragma unroll
  for (int i = 0; i < 6; i++) sreg[i] = *(const s16x8*)sp[i];
#pragma unroll
  for (int i = 0; i < 6; i++) *(s16x8*)sdst[i] = sreg[i];
#pragma unroll
  for (int i = 0; i < 6; i++) sreg[i] = *(const s16x8*)(sp[i] + (size_t)sstep[i]);
  __syncthreads();

  for (int t = 0; t < 16; t++) {
    int cur = t & 1, nxt = (t + 1) & 1;
    if (t < 15) {
#pragma unroll
      for (int i = 0; i < 6; i++) *(s16x8*)(sdst[i] + nxt * boff[i]) = sreg[i];
      int t2 = (t + 2) & 15;
#pragma unroll
      for (int i = 0; i < 6; i++)
        sreg[i] = *(const s16x8*)(sp[i] + (size_t)t2 * sstep[i]);
    }

    const short* Kb = Klds + cur * KOFF;
    const short* Vb = Vlds + cur * VOFF;
#pragma unroll
    for (int kb = 0; kb < 2; kb++) {
      f32x16 st = {};
      __builtin_amdgcn_s_setprio(1);
#pragma unroll
      for (int dc = 0; dc < 6; dc++) {
        int c = dc * 2 + hi2;
        int lam = kb * 32 + q31;
        s16x8 kf = *(const s16x8*)(Kb + lam * 104 + c * 8);
        st = __builtin_amdgcn_mfma_f32_32x32x16_bf16(kf, qf[dc], st, 0, 0, 0);
      }
      __builtin_amdgcn_s_setprio(0);

      unsigned u[8];
#pragma unroll
      for (int i = 0; i < 8; i++) {
        float p0 = __builtin_amdgcn_exp2f(st[2 * i]);
        float p1 = __builtin_amdgcn_exp2f(st[2 * i + 1]);
        unsigned w = pack2(p0, p1);
        u[i] = w;
        lsum += asf(w << 16) + asf(w & 0xffff0000u);
      }

      __builtin_amdgcn_s_setprio(1);
#pragma unroll
      for (int half = 0; half < 2; half++) {
        union { unsigned w[4]; s16x8 v; } pa;
#pragma unroll
        for (int wi = 0; wi < 4; wi++) pa.w[wi] = u[half * 4 + wi];
        int kc = kb * 2 + half;
#pragma unroll
        for (int db = 0; db < 3; db++) {
          int d = db * 32 + q31;
          s16x8 vf = *(const s16x8*)(Vb + d * 64 + (((kc * 2 + hi2) ^ (d & 7)) << 3));
          accO[db] = __builtin_amdgcn_mfma_f32_32x32x16_bf16(pa.v, vf, accO[db], 0, 0, 0);
        }
      }
      __builtin_amdgcn_s_setprio(0);
    }
    __syncthreads();
  }

  float s = lsum + __shfl_xor(lsum, 32, 64);
  float rinv = 1.0f / s;
  float rr[16];
#pragma unroll
  for (int r = 0; r < 16; r++)
    rr[r] = __shfl(rinv, (r & 3) + 8 * (r >> 2) + 4 * hi2, 64);

#pragma unroll
  for (int db = 0; db < 3; db++)
#pragma unroll
    for (int r = 0; r < 16; r++) {
      int qrow = qrow0 + (r & 3) + 8 * (r >> 2) + 4 * hi2;
      int d = db * 32 + q31;
      attn_out[((size_t)b * 1024 + qrow) * 768 + h * 96 + d] = f2bf(accO[db][r] * rr[r]);
    }
}

// ---------------- launch ----------------

extern "C" void kernel_launch(void* const* d_in, const int* in_sizes, int n_in,
                              void* d_out, int out_size, void* d_ws, size_t ws_size,
                              hipStream_t stream) {
  const float* x = (const float*)d_in[0];
  const float* Wqkv = (const float*)d_in[1];
  const float* bqkv = (const float*)d_in[2];
  const float* Wout = (const float*)d_in[3];
  const float* bout = (const float*)d_in[4];
  float* out = (float*)d_out;

  char* ws = (char*)d_ws;
  // layout (bytes), total 130,547,712:
  //   xb    @ 0          : 25,165,824  (bf16 x; later reused as attn_out [B][N][768])
  //   wqkvT @ 25165824   :  3,538,944
  //   woutT @ 28704768   :  1,179,648
  //   qkvb  @ 29884416   : 75,497,472  ([16384][2304] bf16; V region unused)
  //   vtb   @ 105381888  : 25,165,824  ([pair][96][1024] bf16)
  short* xb = (short*)ws;
  short* wqkvT = (short*)(ws + 25165824);
  short* woutT = (short*)(ws + 28704768);
  short* qkvb = (short*)(ws + 29884416);
  short* vtb = (short*)(ws + 105381888);

  // fused prep: 12288 cvt_x blocks + 1728 W_qkv tiles + 576 W_out tiles
  prep_kernel<<<14592, 256, 0, stream>>>(x, xb, Wqkv, wqkvT, Wout, woutT);

  // qkv: M=16384 (64 tiles), N=2304 (18 tiles) -> 1152 blocks (mult of 8)
  gemm2<0><<<1152, 512, 0, stream>>>(xb, wqkvT, bqkv, 768, 18, qkvb, vtb, nullptr);
  attn_kernel<<<1024, 256, 0, stream>>>(qkvb, vtb, xb);
  // out: M=16384 (64), N=768 (6) -> 384 blocks (mult of 8)
  gemm2<1><<<384, 512, 0, stream>>>(xb, woutT, bout, 768, 6, nullptr, nullptr, out);
}